// Round 3
// baseline (77994.623 us; speedup 1.0000x reference)
//
#include <hip/hip_runtime.h>

// ---------------- problem constants ----------------
#define Tn   512
#define Bn   64
#define NWG  256
#define NTH  256

// ---------------- ws layout (float words) ----------------
#define OFF_WCOMB 0               // [2048][256]
#define OFF_BC0   524288          // [2048]
#define OFF_EMBG  526336          // [11][2048]
#define OFF_H0T   548864          // [2][512*64]  (zero region starts here)
#define OFF_H1T   (OFF_H0T + 65536)
#define OFF_C0T   (OFF_H1T + 65536)
#define OFF_C1T   (OFF_C0T + 32768)
#define OFF_IBUF  (OFF_C1T + 32768)   // u64[2][704] = 2816 words, 8B aligned
#define OFF_BAR   (OFF_IBUF + 2816)   // barrier cnt/flag + pad
#define WS_WORDS  (OFF_BAR + 32)
#define ZERO_WORDS (WS_WORDS - OFF_H0T)

// out layout: logits [64][512][11] = 360448, zeros 360448, attn 32768
#define OUT_LOGITS_WORDS 360448
#define OUT_TAIL_WORDS   393216

// ---------------- setup kernels ----------------
__global__ void k_wcomb(const float* __restrict__ Wih0, const float* __restrict__ Wp,
                        const float* __restrict__ bp, const float* __restrict__ bih0,
                        const float* __restrict__ bhh0, float* __restrict__ ws) {
    int j = blockIdx.x;            // 0..2047
    int k = threadIdx.x;           // 0..255
    const float* row = Wih0 + (long)j * 1024;
    float acc = 0.f;
    for (int h = 0; h < 512; ++h) acc = fmaf(row[h], Wp[h * 256 + k], acc);
    ws[OFF_WCOMB + j * 256 + k] = acc;
    // bc0[j] = bih0 + bhh0 + dot(Wih0[j,:512], bp)
    __shared__ float s[256];
    s[k] = row[k] * bp[k] + row[256 + k] * bp[256 + k];
    __syncthreads();
    for (int st = 128; st > 0; st >>= 1) { if (k < st) s[k] += s[k + st]; __syncthreads(); }
    if (k == 0) ws[OFF_BC0 + j] = bih0[j] + bhh0[j] + s[0];
}

__global__ void k_embg(const float* __restrict__ emb, const float* __restrict__ Wih0,
                       float* __restrict__ ws) {
    int cls = blockIdx.x >> 3;                       // 0..10
    int j = ((blockIdx.x & 7) << 8) + threadIdx.x;   // 0..2047
    const float* er = emb + cls * 512;
    const float* wr = Wih0 + (long)j * 1024 + 512;
    float acc = 0.f;
    for (int h = 0; h < 512; ++h) acc = fmaf(er[h], wr[h], acc);
    ws[OFF_EMBG + cls * 2048 + j] = acc;
}

// zero state + write diagnostic sentinel (k_main overwrites out[0] at t=1)
__global__ void k_zero(float* __restrict__ ws, float* __restrict__ out) {
    long i = (long)blockIdx.x * blockDim.x + threadIdx.x;
    if (i < ZERO_WORDS) ws[OFF_H0T + i] = 0.f;
    if (i == 0) out[0] = 1000.0f;
}

// ---------------- main persistent kernel ----------------
struct MP {
    const float *mainf, *phys, *Whh0, *Wih1, *Whh1, *bih1, *bhh1, *W1, *b1, *W2, *b2;
    float* ws;
    float* out;
};

struct Seg {
    const float* act;   // base
    long rs;            // row stride (b-major); unused for kmaj
    int kmaj;           // 1: act[k*64+b]   0: act[b*rs+k]
    int klen;
    const float* wgt;   // weight base, row-major
    int wld;
    int wcol0;
};

__device__ __forceinline__ float sigm(float x) { return 1.f / (1.f + expf(-x)); }

__device__ __forceinline__ void resolve(int ch, int nch0, const Seg* sg, int& s, int& k0, int& kc) {
    if (ch < nch0) { s = 0; k0 = ch << 6; }
    else           { s = 1; k0 = (ch - nch0) << 6; }
    kc = sg[s].klen - k0; if (kc > 64) kc = 64;
}

template <int NI>
__device__ __forceinline__ void stage_chunk(int ch, int nch0, const Seg* sg, int j0, int jstride,
                                            int tid, float (*act)[68], float (*wt)[68]) {
    int s, k0, kc; resolve(ch, nch0, sg, s, k0, kc);
    const Seg g = sg[s];
    if (g.kmaj) {
        #pragma unroll
        for (int ii = 0; ii < 4; ++ii) {
            int e = tid + (ii << 8);          // 0..1023 float4 slots
            int b4 = e & 15, kk = e >> 4;     // b4*4 rows, kk 0..63
            if (kk < kc) {
                float4 v = *(const float4*)(g.act + ((long)(k0 + kk) << 6) + (b4 << 2));
                act[(b4 << 2) + 0][kk] = v.x;
                act[(b4 << 2) + 1][kk] = v.y;
                act[(b4 << 2) + 2][kk] = v.z;
                act[(b4 << 2) + 3][kk] = v.w;
            }
        }
    } else {
        #pragma unroll
        for (int ii = 0; ii < 4; ++ii) {
            int e = tid + (ii << 8);
            int k4 = e & 15, bb = e >> 4;     // k4 0..15, bb 0..63
            if ((k4 << 2) < kc) {
                float4 v = *(const float4*)(g.act + (long)bb * g.rs + k0 + (k4 << 2));
                *(float4*)&act[bb][k4 << 2] = v;
            }
        }
    }
    // weights: NI*2 rows of 64
    for (int e = tid; e < ((NI * 2) << 6); e += 256) {
        int rw = e >> 6, kk = e & 63;
        if (kk < kc) {
            int j = (rw >> 1) * jstride + j0 + (rw & 1);
            wt[rw][kk] = g.wgt[(long)j * g.wld + g.wcol0 + k0 + kk];
        }
    }
}

// acc[i] = sum_k act[k] * W[j(i)][k],  j(i) = i*jstride + j0 + c.
// q in {0,1} splits K; owner threads (q==0, tid<128) hold the full sum on return.
template <int NI>
__device__ void mm_quads(const Seg* sg, int nseg, int j0, int jstride, float* acc,
                         int tid, int b, int c, int q,
                         float (*actA)[68], float (*actB)[68],
                         float (*wAr)[68], float (*wBr)[68],
                         float (*red)[64][4]) {
    #pragma unroll
    for (int i = 0; i < NI; ++i) acc[i] = 0.f;
    int nch0 = (sg[0].klen + 63) >> 6;
    int nch  = nch0 + ((nseg > 1) ? ((sg[1].klen + 63) >> 6) : 0);
    int nq0  = (nch + 1) >> 1;
    for (int it = 0; it < nq0; ++it) {
        int chA = it, chB = nq0 + it;
        stage_chunk<NI>(chA, nch0, sg, j0, jstride, tid, actA, wAr);
        if (chB < nch) stage_chunk<NI>(chB, nch0, sg, j0, jstride, tid, actB, wBr);
        __syncthreads();
        int myc = q ? chB : chA;
        if (myc < nch) {
            int s, k0, kc; resolve(myc, nch0, sg, s, k0, kc);
            float (*at)[68] = q ? actB : actA;
            float (*wv)[68] = q ? wBr : wAr;
            int n4 = kc >> 2;
            for (int k4 = 0; k4 < n4; ++k4) {
                float4 a4 = *(const float4*)&at[b][k4 << 2];
                #pragma unroll
                for (int i = 0; i < NI; ++i) {
                    float4 w4 = *(const float4*)&wv[i * 2 + c][k4 << 2];
                    acc[i] = fmaf(a4.x, w4.x, acc[i]);
                    acc[i] = fmaf(a4.y, w4.y, acc[i]);
                    acc[i] = fmaf(a4.z, w4.z, acc[i]);
                    acc[i] = fmaf(a4.w, w4.w, acc[i]);
                }
            }
        }
        __syncthreads();
    }
    if (q == 1) {
        #pragma unroll
        for (int i = 0; i < NI; ++i) red[c][b][i] = acc[i];
    }
    __syncthreads();
    if (q == 0) {
        #pragma unroll
        for (int i = 0; i < NI; ++i) acc[i] += red[c][b][i];
    }
    __syncthreads();
}

__device__ __forceinline__ void gsync(int* bar, int gen) {
    __syncthreads();
    if (threadIdx.x == 0) {
        __threadfence();
        int a = __hip_atomic_fetch_add(bar, 1, __ATOMIC_ACQ_REL, __HIP_MEMORY_SCOPE_AGENT);
        if (a == NWG - 1) {
            __hip_atomic_store(bar, 0, __ATOMIC_RELAXED, __HIP_MEMORY_SCOPE_AGENT);
            __hip_atomic_store(bar + 1, gen, __ATOMIC_RELEASE, __HIP_MEMORY_SCOPE_AGENT);
        } else {
            int v;
            do {
                __builtin_amdgcn_s_sleep(2);
                v = __hip_atomic_load(bar + 1, __ATOMIC_RELAXED, __HIP_MEMORY_SCOPE_AGENT);
            } while (v < gen);
        }
        __threadfence();
    }
    __syncthreads();
}

__global__ void __launch_bounds__(NTH, 1) k_main(MP p) {
    float* ws = p.ws;
    const float* Wcomb = ws + OFF_WCOMB;
    const float* bc0v  = ws + OFF_BC0;
    const float* embg  = ws + OFF_EMBG;
    float* h0T = ws + OFF_H0T;   // [2][512*64] k-major
    float* h1T = ws + OFF_H1T;
    float* c0T = ws + OFF_C0T;   // [512*64]
    float* c1T = ws + OFF_C1T;
    unsigned long long* ibuf = (unsigned long long*)(ws + OFF_IBUF);  // [2][704]
    int* bar = (int*)(ws + OFF_BAR);

    __shared__ float actA[64][68], actB[64][68];
    __shared__ float wAr[8][68], wBr[8][68];
    __shared__ float red[2][64][4];
    __shared__ float plog[2][64][11];
    __shared__ int prevl[64];

    const int w = blockIdx.x, tid = threadIdx.x;
    const int b = tid & 63, qc = tid >> 6, c = qc & 1, q = qc >> 1;
    int gen = 0;
    const double SC = 4294967296.0;
    const double ISC = 1.0 / 4294967296.0;

    for (int t = 0; t <= Tn; ++t) {
        const int cur = t & 1, prv = cur ^ 1;

        // ---------- Phase A: head for step t-1 (128 WGs, NI=2) ----------
        if (t >= 1 && w < 128) {
            Seg sg[2];
            sg[0] = { h1T + prv * 32768, 0, 1, 512, p.W1, 544, 0 };
            sg[1] = { p.phys + (long)(t - 1) * 32, (long)Tn * 32, 0, 32, p.W1, 544, 512 };
            float acc[2];
            mm_quads<2>(sg, 2, 4 * w, 2, acc, tid, b, c, q, actA, actB, wAr, wBr, red);
            if (q == 0) {
                int jh0 = 4 * w + c, jh1 = 2 + 4 * w + c;
                float r0 = acc[0] + p.b1[jh0]; r0 = r0 > 0.f ? r0 : 0.f;
                float r1 = acc[1] + p.b1[jh1]; r1 = r1 > 0.f ? r1 : 0.f;
                #pragma unroll
                for (int cc = 0; cc < 11; ++cc)
                    plog[c][b][cc] = fmaf(r0, p.W2[cc * 512 + jh0], r1 * p.W2[cc * 512 + jh1]);
            }
            __syncthreads();
            if (tid < 64) {
                unsigned long long* ib = ibuf + prv * 704 + b * 11;
                for (int cc = 0; cc < 11; ++cc) {
                    double v = (double)(plog[0][b][cc] + plog[1][b][cc]);
                    long long qv = __double2ll_rn(v * SC);
                    atomicAdd(&ib[cc], (unsigned long long)qv);
                }
            }
        }
        gsync(bar, ++gen);

        // ---------- Phase B: finalize logits/argmax, gates0 + LSTM0 elementwise ----------
        if (t >= 1) {
            if (tid < 64) {
                const unsigned long long* ib = ibuf + prv * 704 + b * 11;
                float best = -3.4e38f; int am = 0;
                for (int cc = 0; cc < 11; ++cc) {
                    float v = (float)((double)(long long)ib[cc] * ISC) + p.b2[cc];
                    if (w == 0) p.out[(long)b * (Tn * 11) + (long)(t - 1) * 11 + cc] = v;
                    if (v > best) { best = v; am = cc; }
                }
                prevl[b] = am;
            }
        } else {
            if (tid < 64) prevl[b] = 0;
        }
        __syncthreads();
        if (t == Tn) break;
        {
            Seg sg[2];
            sg[0] = { p.mainf + (long)t * 256, (long)Tn * 256, 0, 256, Wcomb, 256, 0 };
            sg[1] = { h0T + prv * 32768, 0, 1, 512, p.Whh0, 512, 0 };
            float acc[4];
            mm_quads<4>(sg, 2, 2 * w, 512, acc, tid, b, c, q, actA, actB, wAr, wBr, red);
            if (q == 0) {
                int k = 2 * w + c;
                int pv = prevl[b];
                const float* eg = embg + pv * 2048;
                float g0 = acc[0] + bc0v[k]        + eg[k];
                float g1 = acc[1] + bc0v[k + 512]  + eg[k + 512];
                float g2 = acc[2] + bc0v[k + 1024] + eg[k + 1024];
                float g3 = acc[3] + bc0v[k + 1536] + eg[k + 1536];
                float ci = c0T[k * 64 + b];
                float cn = sigm(g1) * ci + sigm(g0) * tanhf(g2);
                c0T[k * 64 + b] = cn;
                h0T[cur * 32768 + k * 64 + b] = sigm(g3) * tanhf(cn);
            }
        }
        gsync(bar, ++gen);

        // ---------- Phase C: gates1 + LSTM1 elementwise ----------
        {
            Seg sg[2];
            sg[0] = { h0T + cur * 32768, 0, 1, 512, p.Wih1, 512, 0 };
            sg[1] = { h1T + prv * 32768, 0, 1, 512, p.Whh1, 512, 0 };
            float acc[4];
            mm_quads<4>(sg, 2, 2 * w, 512, acc, tid, b, c, q, actA, actB, wAr, wBr, red);
            if (q == 0) {
                int k = 2 * w + c;
                float g0 = acc[0] + p.bih1[k]        + p.bhh1[k];
                float g1 = acc[1] + p.bih1[k + 512]  + p.bhh1[k + 512];
                float g2 = acc[2] + p.bih1[k + 1024] + p.bhh1[k + 1024];
                float g3 = acc[3] + p.bih1[k + 1536] + p.bhh1[k + 1536];
                float ci = c1T[k * 64 + b];
                float cn = sigm(g1) * ci + sigm(g0) * tanhf(g2);
                c1T[k * 64 + b] = cn;
                h1T[cur * 32768 + k * 64 + b] = sigm(g3) * tanhf(cn);
            }
            if (w == 0) {
                for (int e = tid; e < 704; e += 256) ibuf[cur * 704 + e] = 0ull;
            }
        }
        gsync(bar, ++gen);
    }
}

// ---------------- launch ----------------
extern "C" void kernel_launch(void* const* d_in, const int* in_sizes, int n_in,
                              void* d_out, int out_size, void* d_ws, size_t ws_size,
                              hipStream_t stream) {
    const float* mainf = (const float*)d_in[0];
    const float* phys  = (const float*)d_in[1];
    // d_in[2] = mask (unused)
    const float* Wp   = (const float*)d_in[3];
    const float* bp   = (const float*)d_in[4];
    const float* emb  = (const float*)d_in[5];
    const float* Wih0 = (const float*)d_in[6];
    const float* Whh0 = (const float*)d_in[7];
    const float* bih0 = (const float*)d_in[8];
    const float* bhh0 = (const float*)d_in[9];
    const float* Wih1 = (const float*)d_in[10];
    const float* Whh1 = (const float*)d_in[11];
    const float* bih1 = (const float*)d_in[12];
    const float* bhh1 = (const float*)d_in[13];
    const float* W1   = (const float*)d_in[14];
    const float* b1   = (const float*)d_in[15];
    const float* W2   = (const float*)d_in[16];
    const float* b2   = (const float*)d_in[17];
    float* out = (float*)d_out;
    float* ws  = (float*)d_ws;

    // zeros for output 2 (zeros_like) and output 3 (attn)
    (void)hipMemsetAsync(out + OUT_LOGITS_WORDS, 0, (size_t)OUT_TAIL_WORDS * 4, stream);

    k_wcomb<<<2048, 256, 0, stream>>>(Wih0, Wp, bp, bih0, bhh0, ws);
    k_embg<<<88, 256, 0, stream>>>(emb, Wih0, ws);
    k_zero<<<(ZERO_WORDS + 255) / 256, 256, 0, stream>>>(ws, out);

    MP p{ mainf, phys, Whh0, Wih1, Whh1, bih1, bhh1, W1, b1, W2, b2, ws, out };
    // Plain launch: 256 WGs x 256 thr, 47KB LDS, __launch_bounds__(256,1)
    // => >=2 blocks/CU capacity on 256 CUs, all 256 blocks co-resident.
    // (Round-2 used hipLaunchCooperativeKernel; output was bit-identical to
    //  the no-op stub => launch most likely failed and was swallowed.)
    k_main<<<NWG, NTH, 0, stream>>>(p);
}

// Round 4
// 66183.362 us; speedup vs baseline: 1.1785x; 1.1785x over previous
//
#include <hip/hip_runtime.h>

// ---------------- problem constants ----------------
#define Tn   512
#define Bn   64
#define NWG  256
#define NTH  256

// ---------------- ws layout (float words) ----------------
#define OFF_WCOMB 0               // [2048][256]
#define OFF_BC0   524288          // [2048]
#define OFF_EMBG  526336          // [11][2048]
#define OFF_H0T   548864          // [2][512*64]  (zero region starts here)
#define OFF_H1T   (OFF_H0T + 65536)
#define OFF_C0T   (OFF_H1T + 65536)
#define OFF_C1T   (OFF_C0T + 32768)
#define OFF_IBUF  (OFF_C1T + 32768)   // u64[2][704] = 2816 words, 8B aligned
#define OFF_BAR   (OFF_IBUF + 2816)   // done-flag line (32 words = 128B)
#define OFF_ARR   (OFF_BAR + 32)      // 256 arrival slots * 32 words (128B apart)
#define WS_WORDS  (OFF_ARR + NWG * 32)
#define ZERO_WORDS (WS_WORDS - OFF_H0T)

// out layout: logits [64][512][11] = 360448, zeros 360448, attn 32768
#define OUT_LOGITS_WORDS 360448
#define OUT_TAIL_WORDS   393216

// ---------------- setup kernels ----------------
__global__ void k_wcomb(const float* __restrict__ Wih0, const float* __restrict__ Wp,
                        const float* __restrict__ bp, const float* __restrict__ bih0,
                        const float* __restrict__ bhh0, float* __restrict__ ws) {
    int j = blockIdx.x;            // 0..2047
    int k = threadIdx.x;           // 0..255
    const float* row = Wih0 + (long)j * 1024;
    float acc = 0.f;
    for (int h = 0; h < 512; ++h) acc = fmaf(row[h], Wp[h * 256 + k], acc);
    ws[OFF_WCOMB + j * 256 + k] = acc;
    // bc0[j] = bih0 + bhh0 + dot(Wih0[j,:512], bp)
    __shared__ float s[256];
    s[k] = row[k] * bp[k] + row[256 + k] * bp[256 + k];
    __syncthreads();
    for (int st = 128; st > 0; st >>= 1) { if (k < st) s[k] += s[k + st]; __syncthreads(); }
    if (k == 0) ws[OFF_BC0 + j] = bih0[j] + bhh0[j] + s[0];
}

__global__ void k_embg(const float* __restrict__ emb, const float* __restrict__ Wih0,
                       float* __restrict__ ws) {
    int cls = blockIdx.x >> 3;                       // 0..10
    int j = ((blockIdx.x & 7) << 8) + threadIdx.x;   // 0..2047
    const float* er = emb + cls * 512;
    const float* wr = Wih0 + (long)j * 1024 + 512;
    float acc = 0.f;
    for (int h = 0; h < 512; ++h) acc = fmaf(er[h], wr[h], acc);
    ws[OFF_EMBG + cls * 2048 + j] = acc;
}

// zero state + barrier slots (MUST run every launch: graph replays reuse ws)
__global__ void k_zero(float* __restrict__ ws) {
    long i = (long)blockIdx.x * blockDim.x + threadIdx.x;
    if (i < ZERO_WORDS) ws[OFF_H0T + i] = 0.f;
}

// ---------------- main persistent kernel ----------------
struct MP {
    const float *mainf, *phys, *Whh0, *Wih1, *Whh1, *bih1, *bhh1, *W1, *b1, *W2, *b2;
    float* ws;
    float* out;
};

struct Seg {
    const float* act;   // base
    long rs;            // row stride (b-major); unused for kmaj
    int kmaj;           // 1: act[k*64+b]   0: act[b*rs+k]
    int klen;
    const float* wgt;   // weight base, row-major
    int wld;
    int wcol0;
};

__device__ __forceinline__ float sigm(float x) { return 1.f / (1.f + expf(-x)); }

__device__ __forceinline__ void resolve(int ch, int nch0, const Seg* sg, int& s, int& k0, int& kc) {
    if (ch < nch0) { s = 0; k0 = ch << 6; }
    else           { s = 1; k0 = (ch - nch0) << 6; }
    kc = sg[s].klen - k0; if (kc > 64) kc = 64;
}

// LDS act tile is TRANSPOSED: actT[k_within_chunk][batch], row stride 72.
// 72 % 32 == 8 -> staging float4 writes (k const per quarter-wave, b4 spread)
// and compute b32 reads (lane==batch, consecutive banks) are conflict-free.
template <int NI>
__device__ __forceinline__ void stage_chunk(int ch, int nch0, const Seg* sg, int j0, int jstride,
                                            int tid, float (*act)[72], float (*wt)[68]) {
    int s, k0, kc; resolve(ch, nch0, sg, s, k0, kc);
    const Seg g = sg[s];
    if (g.kmaj) {
        // global: [k][64b] -> lane reads float4 along b (coalesced),
        // LDS: float4 write to actT[kk][4*b4]
        #pragma unroll
        for (int ii = 0; ii < 4; ++ii) {
            int e = tid + (ii << 8);          // 0..1023
            int b4 = e & 15, kk = e >> 4;     // b4: float4-of-batch, kk: 0..63
            if (kk < kc) {
                float4 v = *(const float4*)(g.act + ((long)(k0 + kk) << 6) + (b4 << 2));
                *(float4*)&act[kk][b4 << 2] = v;
            }
        }
    } else {
        // global: [b][K] -> lane bb reads float4 along k,
        // LDS: 4 scalar writes actT[4k4+j][bb] (banks spread by bb, 2-way)
        #pragma unroll
        for (int ii = 0; ii < 4; ++ii) {
            int e = tid + (ii << 8);
            int k4 = e >> 6, bb = e & 63;     // k4 0..15, bb 0..63
            if ((k4 << 2) < kc) {
                float4 v = *(const float4*)(g.act + (long)bb * g.rs + k0 + (k4 << 2));
                act[(k4 << 2) + 0][bb] = v.x;
                act[(k4 << 2) + 1][bb] = v.y;
                act[(k4 << 2) + 2][bb] = v.z;
                act[(k4 << 2) + 3][bb] = v.w;
            }
        }
    }
    // weights: NI*2 rows of 64 (row-major, broadcast-read in compute)
    for (int e = tid; e < ((NI * 2) << 6); e += 256) {
        int rw = e >> 6, kk = e & 63;
        if (kk < kc) {
            int j = (rw >> 1) * jstride + j0 + (rw & 1);
            wt[rw][kk] = g.wgt[(long)j * g.wld + g.wcol0 + k0 + kk];
        }
    }
}

// acc[i] = sum_k act[k] * W[j(i)][k],  j(i) = i*jstride + j0 + c.
// q in {0,1} splits K; owner threads (q==0, tid<128) hold the full sum on return.
template <int NI>
__device__ void mm_quads(const Seg* sg, int nseg, int j0, int jstride, float* acc,
                         int tid, int b, int c, int q,
                         float (*actA)[72], float (*actB)[72],
                         float (*wAr)[68], float (*wBr)[68],
                         float (*red)[64][4]) {
    #pragma unroll
    for (int i = 0; i < NI; ++i) acc[i] = 0.f;
    int nch0 = (sg[0].klen + 63) >> 6;
    int nch  = nch0 + ((nseg > 1) ? ((sg[1].klen + 63) >> 6) : 0);
    int nq0  = (nch + 1) >> 1;
    for (int it = 0; it < nq0; ++it) {
        int chA = it, chB = nq0 + it;
        stage_chunk<NI>(chA, nch0, sg, j0, jstride, tid, actA, wAr);
        if (chB < nch) stage_chunk<NI>(chB, nch0, sg, j0, jstride, tid, actB, wBr);
        __syncthreads();
        int myc = q ? chB : chA;
        if (myc < nch) {
            int s, k0, kc; resolve(myc, nch0, sg, s, k0, kc);
            float (*at)[72] = q ? actB : actA;
            float (*wv)[68] = q ? wBr : wAr;
            int n4 = kc >> 2;
            for (int k4 = 0; k4 < n4; ++k4) {
                float a0 = at[(k4 << 2) + 0][b];
                float a1 = at[(k4 << 2) + 1][b];
                float a2 = at[(k4 << 2) + 2][b];
                float a3 = at[(k4 << 2) + 3][b];
                #pragma unroll
                for (int i = 0; i < NI; ++i) {
                    float4 w4 = *(const float4*)&wv[i * 2 + c][k4 << 2];
                    acc[i] = fmaf(a0, w4.x, acc[i]);
                    acc[i] = fmaf(a1, w4.y, acc[i]);
                    acc[i] = fmaf(a2, w4.z, acc[i]);
                    acc[i] = fmaf(a3, w4.w, acc[i]);
                }
            }
        }
        __syncthreads();
    }
    if (q == 1) {
        #pragma unroll
        for (int i = 0; i < NI; ++i) red[c][b][i] = acc[i];
    }
    __syncthreads();
    if (q == 0) {
        #pragma unroll
        for (int i = 0; i < NI; ++i) acc[i] += red[c][b][i];
    }
    __syncthreads();
}

// Contention-free broadcast barrier: per-WG arrival slot (release store),
// WG0 aggregates (256 threads poll 1 slot each), publishes done=gen.
// No RMW anywhere. State zeroed by k_zero each launch.
__device__ __forceinline__ void gsync(int* done, int* arr, int w, int gen) {
    __syncthreads();
    const int tid = threadIdx.x;
    if (tid == 0) {
        __threadfence();
        __hip_atomic_store(&arr[w * 32], gen, __ATOMIC_RELEASE, __HIP_MEMORY_SCOPE_AGENT);
    }
    if (w == 0) {
        int v;
        do {
            __builtin_amdgcn_s_sleep(1);
            v = __hip_atomic_load(&arr[tid * 32], __ATOMIC_RELAXED, __HIP_MEMORY_SCOPE_AGENT);
        } while (v < gen);
        __syncthreads();
        if (tid == 0) {
            __threadfence();
            __hip_atomic_store(done, gen, __ATOMIC_RELEASE, __HIP_MEMORY_SCOPE_AGENT);
        }
    } else {
        if (tid == 0) {
            int v;
            do {
                __builtin_amdgcn_s_sleep(2);
                v = __hip_atomic_load(done, __ATOMIC_RELAXED, __HIP_MEMORY_SCOPE_AGENT);
            } while (v < gen);
            __threadfence();
        }
    }
    __syncthreads();
}

__global__ void __launch_bounds__(NTH, 1) k_main(MP p) {
    float* ws = p.ws;
    const float* Wcomb = ws + OFF_WCOMB;
    const float* bc0v  = ws + OFF_BC0;
    const float* embg  = ws + OFF_EMBG;
    float* h0T = ws + OFF_H0T;   // [2][512*64] k-major
    float* h1T = ws + OFF_H1T;
    float* c0T = ws + OFF_C0T;   // [512*64]
    float* c1T = ws + OFF_C1T;
    unsigned long long* ibuf = (unsigned long long*)(ws + OFF_IBUF);  // [2][704]
    int* done = (int*)(ws + OFF_BAR);
    int* arr  = (int*)(ws + OFF_ARR);

    __shared__ float actA[64][72], actB[64][72];
    __shared__ float wAr[8][68], wBr[8][68];
    __shared__ float red[2][64][4];
    __shared__ float plog[2][64][11];
    __shared__ int prevl[64];

    const int w = blockIdx.x, tid = threadIdx.x;
    const int b = tid & 63, qc = tid >> 6, c = qc & 1, q = qc >> 1;
    int gen = 0;
    const double SC = 4294967296.0;
    const double ISC = 1.0 / 4294967296.0;

    for (int t = 0; t <= Tn; ++t) {
        const int cur = t & 1, prv = cur ^ 1;

        // ---------- Phase A: head for step t-1 (128 WGs, NI=2) ----------
        if (t >= 1 && w < 128) {
            Seg sg[2];
            sg[0] = { h1T + prv * 32768, 0, 1, 512, p.W1, 544, 0 };
            sg[1] = { p.phys + (long)(t - 1) * 32, (long)Tn * 32, 0, 32, p.W1, 544, 512 };
            float acc[2];
            mm_quads<2>(sg, 2, 4 * w, 2, acc, tid, b, c, q, actA, actB, wAr, wBr, red);
            if (q == 0) {
                int jh0 = 4 * w + c, jh1 = 2 + 4 * w + c;
                float r0 = acc[0] + p.b1[jh0]; r0 = r0 > 0.f ? r0 : 0.f;
                float r1 = acc[1] + p.b1[jh1]; r1 = r1 > 0.f ? r1 : 0.f;
                #pragma unroll
                for (int cc = 0; cc < 11; ++cc)
                    plog[c][b][cc] = fmaf(r0, p.W2[cc * 512 + jh0], r1 * p.W2[cc * 512 + jh1]);
            }
            __syncthreads();
            if (tid < 64) {
                unsigned long long* ib = ibuf + prv * 704 + b * 11;
                for (int cc = 0; cc < 11; ++cc) {
                    double v = (double)(plog[0][b][cc] + plog[1][b][cc]);
                    long long qv = __double2ll_rn(v * SC);
                    atomicAdd(&ib[cc], (unsigned long long)qv);
                }
            }
        }
        gsync(done, arr, w, ++gen);

        // ---------- Phase B: finalize logits/argmax, gates0 + LSTM0 elementwise ----------
        if (t >= 1) {
            if (tid < 64) {
                const unsigned long long* ib = ibuf + prv * 704 + b * 11;
                float best = -3.4e38f; int am = 0;
                for (int cc = 0; cc < 11; ++cc) {
                    float v = (float)((double)(long long)ib[cc] * ISC) + p.b2[cc];
                    if (w == 0) p.out[(long)b * (Tn * 11) + (long)(t - 1) * 11 + cc] = v;
                    if (v > best) { best = v; am = cc; }
                }
                prevl[b] = am;
            }
        } else {
            if (tid < 64) prevl[b] = 0;
        }
        __syncthreads();
        if (t == Tn) break;
        {
            Seg sg[2];
            sg[0] = { p.mainf + (long)t * 256, (long)Tn * 256, 0, 256, Wcomb, 256, 0 };
            sg[1] = { h0T + prv * 32768, 0, 1, 512, p.Whh0, 512, 0 };
            float acc[4];
            mm_quads<4>(sg, 2, 2 * w, 512, acc, tid, b, c, q, actA, actB, wAr, wBr, red);
            if (q == 0) {
                int k = 2 * w + c;
                int pv = prevl[b];
                const float* eg = embg + pv * 2048;
                float g0 = acc[0] + bc0v[k]        + eg[k];
                float g1 = acc[1] + bc0v[k + 512]  + eg[k + 512];
                float g2 = acc[2] + bc0v[k + 1024] + eg[k + 1024];
                float g3 = acc[3] + bc0v[k + 1536] + eg[k + 1536];
                float ci = c0T[k * 64 + b];
                float cn = sigm(g1) * ci + sigm(g0) * tanhf(g2);
                c0T[k * 64 + b] = cn;
                h0T[cur * 32768 + k * 64 + b] = sigm(g3) * tanhf(cn);
            }
        }
        gsync(done, arr, w, ++gen);

        // ---------- Phase C: gates1 + LSTM1 elementwise ----------
        {
            Seg sg[2];
            sg[0] = { h0T + cur * 32768, 0, 1, 512, p.Wih1, 512, 0 };
            sg[1] = { h1T + prv * 32768, 0, 1, 512, p.Whh1, 512, 0 };
            float acc[4];
            mm_quads<4>(sg, 2, 2 * w, 512, acc, tid, b, c, q, actA, actB, wAr, wBr, red);
            if (q == 0) {
                int k = 2 * w + c;
                float g0 = acc[0] + p.bih1[k]        + p.bhh1[k];
                float g1 = acc[1] + p.bih1[k + 512]  + p.bhh1[k + 512];
                float g2 = acc[2] + p.bih1[k + 1024] + p.bhh1[k + 1024];
                float g3 = acc[3] + p.bih1[k + 1536] + p.bhh1[k + 1536];
                float ci = c1T[k * 64 + b];
                float cn = sigm(g1) * ci + sigm(g0) * tanhf(g2);
                c1T[k * 64 + b] = cn;
                h1T[cur * 32768 + k * 64 + b] = sigm(g3) * tanhf(cn);
            }
            if (w == 0) {
                for (int e = tid; e < 704; e += 256) ibuf[cur * 704 + e] = 0ull;
            }
        }
        gsync(done, arr, w, ++gen);
    }
}

// ---------------- launch ----------------
extern "C" void kernel_launch(void* const* d_in, const int* in_sizes, int n_in,
                              void* d_out, int out_size, void* d_ws, size_t ws_size,
                              hipStream_t stream) {
    const float* mainf = (const float*)d_in[0];
    const float* phys  = (const float*)d_in[1];
    // d_in[2] = mask (unused)
    const float* Wp   = (const float*)d_in[3];
    const float* bp   = (const float*)d_in[4];
    const float* emb  = (const float*)d_in[5];
    const float* Wih0 = (const float*)d_in[6];
    const float* Whh0 = (const float*)d_in[7];
    const float* bih0 = (const float*)d_in[8];
    const float* bhh0 = (const float*)d_in[9];
    const float* Wih1 = (const float*)d_in[10];
    const float* Whh1 = (const float*)d_in[11];
    const float* bih1 = (const float*)d_in[12];
    const float* bhh1 = (const float*)d_in[13];
    const float* W1   = (const float*)d_in[14];
    const float* b1   = (const float*)d_in[15];
    const float* W2   = (const float*)d_in[16];
    const float* b2   = (const float*)d_in[17];
    float* out = (float*)d_out;
    float* ws  = (float*)d_ws;

    // zeros for output 2 (zeros_like) and output 3 (attn)
    (void)hipMemsetAsync(out + OUT_LOGITS_WORDS, 0, (size_t)OUT_TAIL_WORDS * 4, stream);

    k_wcomb<<<2048, 256, 0, stream>>>(Wih0, Wp, bp, bih0, bhh0, ws);
    k_embg<<<88, 256, 0, stream>>>(emb, Wih0, ws);
    k_zero<<<(ZERO_WORDS + 255) / 256, 256, 0, stream>>>(ws);

    MP p{ mainf, phys, Whh0, Wih1, Whh1, bih1, bhh1, W1, b1, W2, b2, ws, out };
    k_main<<<NWG, NTH, 0, stream>>>(p);
}